// Round 20
// baseline (57.116 us; speedup 1.0000x reference)
//
#include <hip/hip_runtime.h>
#include <math.h>

#define NN 50000
#define NE 500000
#define FD 8
#define EFD 4
#define TD 12
#define CD 32
#define FT (FD*TD)   // 96
#define SLOTS 48     // fixed slots per node (Poisson(5): P(deg>48) ~ 1e-35)
#define ZB 49        // zero blocks: 49*512=25088 >= 25000 float4 (NN u64)
#define ZV4 25000
#define L2E 1.4426950408889634f
#define MASK56 ((1ULL << 56) - 1)
#define K56 (1.0f / 4294967296.0f)
#define GN 4         // nodes per kGE block (128 threads = 2 waves)

typedef float f32x2 __attribute__((ext_vector_type(2)));

// ---------------- Kernel Init: zero dc[] + weight fold ----------------------
// consts layout (floats): Mz[256] Mh[256] az[32] ah[32] cz[32] ch[32] p[12]
// z-gate entries pre-scaled by log2(e), h-gate by 2*log2(e): cell phase uses
// raw v_exp_f32 (2^x) with no pre-multiply.
__global__ __launch_bounds__(512) void kInit(
    float4* __restrict__ zp,
    const float* __restrict__ feat_W, const float* __restrict__ feat_b,
    const float* __restrict__ attention,
    const float* __restrict__ conv_z_W, const float* __restrict__ conv_z_b,
    const float* __restrict__ conv_h_W, const float* __restrict__ conv_h_b,
    const float* __restrict__ lin_z_W, const float* __restrict__ lin_z_b,
    const float* __restrict__ lin_h_W, const float* __restrict__ lin_h_b,
    float* __restrict__ consts)
{
    int tid = threadIdx.x;
    if (blockIdx.x < ZB) {
        int i = blockIdx.x * 512 + tid;
        if (i < ZV4) zp[i] = make_float4(0.f, 0.f, 0.f, 0.f);
        return;
    }
    // ---- fold block ----
    __shared__ float WL[2][FD*CD];
    int half = tid >> 8;          // 0 -> z, 1 -> h
    int idx  = tid & 255;         // f*32 + c
    int f = idx >> 5, c = idx & 31;
    float scale = half ? 2.f * L2E : L2E;
    const float* convW = half ? conv_h_W : conv_z_W;
    const float* linW  = half ? lin_h_W  : lin_z_W;   // rows 0..C-1 (gcn part)
    float acc = 0.f;
    #pragma unroll
    for (int k = 0; k < CD; ++k)
        acc += convW[f*CD + k] * linW[k*CD + c];
    WL[half][idx] = acc;
    __syncthreads();
    float m = 0.f;
    #pragma unroll
    for (int g = 0; g < FD; ++g)
        m += feat_W[f*FD + g] * WL[half][g*CD + c];
    consts[half*256 + idx] = m * scale;   // Mz / Mh (scaled)
    if (f == 0) {
        float a = 0.f;
        #pragma unroll
        for (int g = 0; g < FD; ++g)
            a += feat_b[g] * WL[half][g*CD + c];
        consts[512 + half*32 + c] = a * scale;       // az / ah (scaled)
        const float* convB = half ? conv_h_b : conv_z_b;
        const float* linB  = half ? lin_h_b : lin_z_b;
        float cc = linB[c];
        #pragma unroll
        for (int k = 0; k < CD; ++k)
            cc += convB[k] * linW[k*CD + c];
        consts[576 + half*32 + c] = cc * scale;      // cz / ch (scaled)
    }
    if (tid == 0) {
        float mx = attention[0];
        for (int t = 1; t < TD; ++t) mx = fmaxf(mx, attention[t]);
        float e[TD], sum = 0.f;
        for (int t = 0; t < TD; ++t) { e[t] = expf(attention[t] - mx); sum += e[t]; }
        for (int t = 0; t < TD; ++t) consts[640 + t] = e[t] / sum;
    }
}

// ------- Kernel B1: edge MLP + ONE packed 64-bit atomic slot-alloc ----------
// dc[c]: high 8 bits = count (slot allocator), low 56 bits = deg sum in
// 2^-32 fixed point. One atomicAdd allocates the slot AND accumulates deg.
__global__ void kB1(const int* __restrict__ ei, const float* __restrict__ ef,
                    const float* __restrict__ ef_W, const float* __restrict__ ef_b,
                    unsigned long long* __restrict__ dc, int2* __restrict__ ep)
{
    int e = blockIdx.x * blockDim.x + threadIdx.x;
    if (e >= NE) return;
    float4 f4 = ((const float4*)ef)[e];
    float w = ef_b[0] + f4.x*ef_W[0] + f4.y*ef_W[1] + f4.z*ef_W[2] + f4.w*ef_W[3];
    if (w <= 0.f) return;    // relu'd-to-zero edges contribute nothing
    int r = ei[e], c = ei[NE + e];
    unsigned long long pack = (1ULL << 56)
        | (unsigned long long)(w * 4294967296.0f);  // w*2^32, < 2^40
    unsigned long long old = atomicAdd(&dc[c], pack);
    int pos = (int)(old >> 56);
    if (pos < SLOTS) ep[c * SLOTS + pos] = make_int2(r, __float_as_int(w));
}

// ---------------- Kernel GE: fused slot gather + cell + head ----------------
// 128 threads = 2 waves = 4 nodes: 16 WG/CU x 2 waves = full 32-wave budget,
// minimal barrier coupling. Slot metadata m-predicated on owner lane,
// broadcast in-register via __shfl. dinv computed on the fly from dc.
__global__ __launch_bounds__(128) void kGE(
    const float* __restrict__ x, const unsigned long long* __restrict__ dc,
    const int2* __restrict__ ep, const float* __restrict__ consts,
    const float* __restrict__ head_W, const float* __restrict__ head_b,
    float* __restrict__ out)
{
    __shared__ float headW[CD*TD];   // 384 floats
    __shared__ float ylds[GN*FT];
    __shared__ float hlds[GN*33];
    int tid = threadIdx.x;           // 0..127
    int c0 = tid & 31;               // lane within node == channel
    int gg = tid >> 5;               // node within block (0..3)
    // per-lane register constants (coalesced global loads; consts is L2-hot)
    float mzr[FD], mhr[FD];
    #pragma unroll
    for (int f = 0; f < FD; ++f) {
        mzr[f] = consts[f*CD + c0];
        mhr[f] = consts[256 + f*CD + c0];
    }
    float azc = consts[512 + c0], ahc = consts[544 + c0];
    float czc = consts[576 + c0], chc = consts[608 + c0];
    float pt[TD];
    #pragma unroll
    for (int t = 0; t < TD; ++t) pt[t] = consts[640 + t];   // uniform -> s_load
    #pragma unroll
    for (int k = 0; k < 3; ++k) headW[tid + 128*k] = head_W[tid + 128*k];
    int n = blockIdx.x * GN + gg;

    // ---- gather phase ----
    unsigned long long vn = dc[n];                  // broadcast (per half-wave)
    float di = rsqrtf((float)(vn & MASK56) * K56 + 1.0f);
    float d2 = di * di;
    int m = (int)(vn >> 56);
    if (m > SLOTS) m = SLOTS;
    const float* xrow = x + (size_t)n * FT + c0 * 3;
    float3 xs = *(const float3*)xrow;
    float acc0 = d2*xs.x, acc1 = d2*xs.y, acc2 = d2*xs.z;
    int st = n * SLOTS;
    // owner lane (c0&7) loads slot (c0&7) if valid; else self/zero
    int slot = c0 & 7;
    int2 q = make_int2(n, 0);
    float vvl = 0.f;
    if (slot < m) {
        q = ep[st + slot];
        unsigned long long sd = dc[q.x];
        float ds = rsqrtf((float)(sd & MASK56) * K56 + 1.0f);
        vvl = __int_as_float(q.y) * ds * di;
    }
    float sv = d2;
    #pragma unroll
    for (int i = 0; i < 8; ++i) {
        int   si = __shfl(q.x, i, 32);
        float vi = __shfl(vvl, i, 32);
        float3 xr = *(const float3*)(x + (size_t)si * FT + c0 * 3);
        acc0 += vi*xr.x; acc1 += vi*xr.y; acc2 += vi*xr.z;
        sv += vi;
    }
    // tail for deg > 8 (~13% of nodes): raw (src,w) slots, per-lane redundant
    for (int j = st + 8, en = st + m; j < en; ++j) {
        int2 p0 = ep[j];
        unsigned long long td = dc[p0.x];
        float tds = rsqrtf((float)(td & MASK56) * K56 + 1.0f);
        float v0 = __int_as_float(p0.y) * tds * di;
        float3 xr = *(const float3*)(x + (size_t)p0.x * FT + c0 * 3);
        acc0 += v0*xr.x; acc1 += v0*xr.y; acc2 += v0*xr.z;
        sv += v0;
    }
    float* yw = ylds + gg * FT + c0 * 3;
    yw[0] = acc0; yw[1] = acc1; yw[2] = acc2;
    float sn = sv;                   // every lane of the node has the full sum
    __syncthreads();                 // 2-wave barrier: cheap

    // ---- cell phase: 32 lanes per node, packed-fp32 FMAs ----
    const float4* yf4 = (const float4*)(ylds + gg * FT);
    float bz = czc + sn * azc;
    float bh = chc + sn * ahc;
    f32x2 pz2[6], ph2[6];
    #pragma unroll
    for (int k = 0; k < 6; ++k) {
        pz2[k].x = bz; pz2[k].y = bz;
        ph2[k].x = bh; ph2[k].y = bh;
    }
    #pragma unroll
    for (int f = 0; f < FD; ++f) {
        float4 ya = yf4[f*3 + 0], yb = yf4[f*3 + 1], yc = yf4[f*3 + 2];
        f32x2 y2[6];
        y2[0].x = ya.x; y2[0].y = ya.y;  y2[1].x = ya.z; y2[1].y = ya.w;
        y2[2].x = yb.x; y2[2].y = yb.y;  y2[3].x = yb.z; y2[3].y = yb.w;
        y2[4].x = yc.x; y2[4].y = yc.y;  y2[5].x = yc.z; y2[5].y = yc.w;
        f32x2 mz2, mh2;
        mz2.x = mzr[f]; mz2.y = mzr[f];
        mh2.x = mhr[f]; mh2.y = mhr[f];
        #pragma unroll
        for (int k = 0; k < 6; ++k) {
            asm volatile("v_pk_fma_f32 %0, %1, %2, %0"
                         : "+v"(pz2[k]) : "v"(y2[k]), "v"(mz2));
            asm volatile("v_pk_fma_f32 %0, %1, %2, %0"
                         : "+v"(ph2[k]) : "v"(y2[k]), "v"(mh2));
        }
    }
    float acc = 0.f;
    #pragma unroll
    for (int k = 0; k < 6; ++k) {
        #pragma unroll
        for (int h = 0; h < 2; ++h) {
            float pzv = (h == 0) ? pz2[k].x : pz2[k].y;
            float phv = (h == 0) ? ph2[k].x : ph2[k].y;
            // weights pre-scaled by log2e (z) / 2*log2e (h):
            // (1-z) = 1/(1+2^pz); tanh = 1 - 2/(1+2^ph)
            float ez, eh;
            asm("v_exp_f32 %0, %1" : "=v"(ez) : "v"(pzv));
            asm("v_exp_f32 %0, %1" : "=v"(eh) : "v"(phv));
            float omz = __builtin_amdgcn_rcpf(1.f + ez);
            float th  = 1.f - 2.f * __builtin_amdgcn_rcpf(1.f + eh);
            acc += pt[2*k + h] * omz * th;
        }
    }
    hlds[gg*33 + c0] = fmaxf(acc, 0.f);
    __syncthreads();

    // ---- head phase: GN nodes x 12 outputs ----
    if (tid < GN*TD) {
        int n0 = tid / TD, tt = tid - n0*TD;
        float v = head_b[tt];
        const float* hn = hlds + n0*33;
        #pragma unroll
        for (int cc = 0; cc < CD; ++cc) v += hn[cc] * headW[cc*TD + tt];
        out[(size_t)(blockIdx.x*GN + n0)*TD + tt] = v;
    }
}

extern "C" void kernel_launch(void* const* d_in, const int* in_sizes, int n_in,
                              void* d_out, int out_size, void* d_ws, size_t ws_size,
                              hipStream_t stream)
{
    const float* x      = (const float*)d_in[0];
    const int*   ei     = (const int*)  d_in[1];
    const float* ef     = (const float*)d_in[2];
    const float* feat_W = (const float*)d_in[3];
    const float* feat_b = (const float*)d_in[4];
    const float* ef_W   = (const float*)d_in[5];
    const float* ef_b   = (const float*)d_in[6];
    const float* att    = (const float*)d_in[7];
    const float* czW    = (const float*)d_in[8];
    const float* czb    = (const float*)d_in[9];
    const float* chW    = (const float*)d_in[12];
    const float* chb    = (const float*)d_in[13];
    const float* lzW    = (const float*)d_in[14];
    const float* lzb    = (const float*)d_in[15];
    const float* lhW    = (const float*)d_in[18];
    const float* lhb    = (const float*)d_in[19];
    const float* hW     = (const float*)d_in[20];
    const float* hb     = (const float*)d_in[21];
    float* out = (float*)d_out;

    unsigned long long* dc  = (unsigned long long*)d_ws;   // NN u64 (zeroed)
    float*              cst = (float*)(dc + NN);           // 1024
    int2*               ep  = (int2*)(cst + 1024);         // NN*SLOTS pairs

    kInit<<<ZB + 1, 512, 0, stream>>>((float4*)dc, feat_W, feat_b, att,
                                      czW, czb, chW, chb, lzW, lzb, lhW, lhb, cst);
    kB1<<<(NE + 255)/256, 256, 0, stream>>>(ei, ef, ef_W, ef_b, dc, ep);
    kGE<<<(NN + GN - 1)/GN, 128, 0, stream>>>(x, dc, ep, cst, hW, hb, out);
}

// Round 21
// 56.009 us; speedup vs baseline: 1.0198x; 1.0198x over previous
//
#include <hip/hip_runtime.h>
#include <math.h>

#define NN 50000
#define NE 500000
#define FD 8
#define EFD 4
#define TD 12
#define CD 32
#define FT (FD*TD)   // 96
#define SLOTS 48     // fixed slots per node (Poisson(5): P(deg>48) ~ 1e-35)
#define ZB 49        // zero blocks: 49*512=25088 >= 25000 float4 (NN u64)
#define ZV4 25000
#define L2E 1.4426950408889634f
#define MASK56 ((1ULL << 56) - 1)
#define K56 (1.0f / 4294967296.0f)

typedef float f32x2 __attribute__((ext_vector_type(2)));

// ---------------- Kernel Init: zero dc[] + weight fold ----------------------
// consts layout (floats): Mz[256] Mh[256] az[32] ah[32] cz[32] ch[32] p[12]
// z-gate entries pre-scaled by log2(e), h-gate by 2*log2(e): cell phase uses
// raw v_exp_f32 (2^x) with no pre-multiply.
__global__ __launch_bounds__(512) void kInit(
    float4* __restrict__ zp,
    const float* __restrict__ feat_W, const float* __restrict__ feat_b,
    const float* __restrict__ attention,
    const float* __restrict__ conv_z_W, const float* __restrict__ conv_z_b,
    const float* __restrict__ conv_h_W, const float* __restrict__ conv_h_b,
    const float* __restrict__ lin_z_W, const float* __restrict__ lin_z_b,
    const float* __restrict__ lin_h_W, const float* __restrict__ lin_h_b,
    float* __restrict__ consts)
{
    int tid = threadIdx.x;
    if (blockIdx.x < ZB) {
        int i = blockIdx.x * 512 + tid;
        if (i < ZV4) zp[i] = make_float4(0.f, 0.f, 0.f, 0.f);
        return;
    }
    // ---- fold block ----
    __shared__ float WL[2][FD*CD];
    int half = tid >> 8;          // 0 -> z, 1 -> h
    int idx  = tid & 255;         // f*32 + c
    int f = idx >> 5, c = idx & 31;
    float scale = half ? 2.f * L2E : L2E;
    const float* convW = half ? conv_h_W : conv_z_W;
    const float* linW  = half ? lin_h_W  : lin_z_W;   // rows 0..C-1 (gcn part)
    float acc = 0.f;
    #pragma unroll
    for (int k = 0; k < CD; ++k)
        acc += convW[f*CD + k] * linW[k*CD + c];
    WL[half][idx] = acc;
    __syncthreads();
    float m = 0.f;
    #pragma unroll
    for (int g = 0; g < FD; ++g)
        m += feat_W[f*FD + g] * WL[half][g*CD + c];
    consts[half*256 + idx] = m * scale;   // Mz / Mh (scaled)
    if (f == 0) {
        float a = 0.f;
        #pragma unroll
        for (int g = 0; g < FD; ++g)
            a += feat_b[g] * WL[half][g*CD + c];
        consts[512 + half*32 + c] = a * scale;       // az / ah (scaled)
        const float* convB = half ? conv_h_b : conv_z_b;
        const float* linB  = half ? lin_h_b : lin_z_b;
        float cc = linB[c];
        #pragma unroll
        for (int k = 0; k < CD; ++k)
            cc += convB[k] * linW[k*CD + c];
        consts[576 + half*32 + c] = cc * scale;      // cz / ch (scaled)
    }
    if (tid == 0) {
        float mx = attention[0];
        for (int t = 1; t < TD; ++t) mx = fmaxf(mx, attention[t]);
        float e[TD], sum = 0.f;
        for (int t = 0; t < TD; ++t) { e[t] = expf(attention[t] - mx); sum += e[t]; }
        for (int t = 0; t < TD; ++t) consts[640 + t] = e[t] / sum;
    }
}

// ------- Kernel B1: edge MLP + ONE packed 64-bit atomic slot-alloc ----------
// dc[c]: high 8 bits = count (slot allocator), low 56 bits = deg sum in
// 2^-32 fixed point. One atomicAdd allocates the slot AND accumulates deg.
__global__ void kB1(const int* __restrict__ ei, const float* __restrict__ ef,
                    const float* __restrict__ ef_W, const float* __restrict__ ef_b,
                    unsigned long long* __restrict__ dc, int2* __restrict__ ep)
{
    int e = blockIdx.x * blockDim.x + threadIdx.x;
    if (e >= NE) return;
    float4 f4 = ((const float4*)ef)[e];
    float w = ef_b[0] + f4.x*ef_W[0] + f4.y*ef_W[1] + f4.z*ef_W[2] + f4.w*ef_W[3];
    if (w <= 0.f) return;    // relu'd-to-zero edges contribute nothing
    int r = ei[e], c = ei[NE + e];
    unsigned long long pack = (1ULL << 56)
        | (unsigned long long)(w * 4294967296.0f);  // w*2^32, < 2^40
    unsigned long long old = atomicAdd(&dc[c], pack);
    int pos = (int)(old >> 56);
    if (pos < SLOTS) ep[c * SLOTS + pos] = make_int2(r, __float_as_int(w));
}

// ---------------- Kernel GE: fused slot gather + cell + head ----------------
// ONE WAVE per block (2 nodes): __syncthreads is a trivial single-wave
// barrier, so waves retire independently (no inter-wave latency coupling).
// Slot metadata loaded once per node (owner lane, m-predicated) and
// broadcast in-register via __shfl. dinv computed on the fly from dc.
__global__ __launch_bounds__(64) void kGE(
    const float* __restrict__ x, const unsigned long long* __restrict__ dc,
    const int2* __restrict__ ep, const float* __restrict__ consts,
    const float* __restrict__ head_W, const float* __restrict__ head_b,
    float* __restrict__ out)
{
    __shared__ float headW[CD*TD];   // 384 floats
    __shared__ float ylds[2*FT];     // 192 floats
    __shared__ float hlds[2*33];
    int tid = threadIdx.x;           // 0..63
    int c0 = tid & 31;               // lane within node == channel
    int gg = tid >> 5;               // node within block (0..1)
    // per-lane register constants (coalesced global loads; consts is L2-hot)
    float mzr[FD], mhr[FD];
    #pragma unroll
    for (int f = 0; f < FD; ++f) {
        mzr[f] = consts[f*CD + c0];
        mhr[f] = consts[256 + f*CD + c0];
    }
    float azc = consts[512 + c0], ahc = consts[544 + c0];
    float czc = consts[576 + c0], chc = consts[608 + c0];
    float pt[TD];
    #pragma unroll
    for (int t = 0; t < TD; ++t) pt[t] = consts[640 + t];   // uniform -> s_load
    #pragma unroll
    for (int k = 0; k < 6; ++k) headW[tid + 64*k] = head_W[tid + 64*k];
    int n = blockIdx.x * 2 + gg;

    // ---- gather phase ----
    unsigned long long vn = dc[n];                  // broadcast (per half-wave)
    float di = rsqrtf((float)(vn & MASK56) * K56 + 1.0f);
    float d2 = di * di;
    int m = (int)(vn >> 56);
    if (m > SLOTS) m = SLOTS;
    const float* xrow = x + (size_t)n * FT + c0 * 3;
    float3 xs = *(const float3*)xrow;
    float acc0 = d2*xs.x, acc1 = d2*xs.y, acc2 = d2*xs.z;
    int st = n * SLOTS;
    // owner lane (c0&7) loads slot (c0&7) if valid; else self/zero
    int slot = c0 & 7;
    int2 q = make_int2(n, 0);
    float vvl = 0.f;
    if (slot < m) {
        q = ep[st + slot];
        unsigned long long sd = dc[q.x];
        float ds = rsqrtf((float)(sd & MASK56) * K56 + 1.0f);
        vvl = __int_as_float(q.y) * ds * di;
    }
    float sv = d2;
    #pragma unroll
    for (int i = 0; i < 8; ++i) {
        int   si = __shfl(q.x, i, 32);
        float vi = __shfl(vvl, i, 32);
        float3 xr = *(const float3*)(x + (size_t)si * FT + c0 * 3);
        acc0 += vi*xr.x; acc1 += vi*xr.y; acc2 += vi*xr.z;
        sv += vi;
    }
    // tail for deg > 8 (~13% of nodes): raw (src,w) slots, per-lane redundant
    for (int j = st + 8, en = st + m; j < en; ++j) {
        int2 p0 = ep[j];
        unsigned long long td = dc[p0.x];
        float tds = rsqrtf((float)(td & MASK56) * K56 + 1.0f);
        float v0 = __int_as_float(p0.y) * tds * di;
        float3 xr = *(const float3*)(x + (size_t)p0.x * FT + c0 * 3);
        acc0 += v0*xr.x; acc1 += v0*xr.y; acc2 += v0*xr.z;
        sv += v0;
    }
    float* yw = ylds + gg * FT + c0 * 3;
    yw[0] = acc0; yw[1] = acc1; yw[2] = acc2;
    float sn = sv;                   // every lane of the node has the full sum
    __syncthreads();                 // single-wave: trivial

    // ---- cell phase: 32 lanes per node, packed-fp32 FMAs ----
    const float4* yf4 = (const float4*)(ylds + gg * FT);
    float bz = czc + sn * azc;
    float bh = chc + sn * ahc;
    f32x2 pz2[6], ph2[6];
    #pragma unroll
    for (int k = 0; k < 6; ++k) {
        pz2[k].x = bz; pz2[k].y = bz;
        ph2[k].x = bh; ph2[k].y = bh;
    }
    #pragma unroll
    for (int f = 0; f < FD; ++f) {
        float4 ya = yf4[f*3 + 0], yb = yf4[f*3 + 1], yc = yf4[f*3 + 2];
        f32x2 y2[6];
        y2[0].x = ya.x; y2[0].y = ya.y;  y2[1].x = ya.z; y2[1].y = ya.w;
        y2[2].x = yb.x; y2[2].y = yb.y;  y2[3].x = yb.z; y2[3].y = yb.w;
        y2[4].x = yc.x; y2[4].y = yc.y;  y2[5].x = yc.z; y2[5].y = yc.w;
        f32x2 mz2, mh2;
        mz2.x = mzr[f]; mz2.y = mzr[f];
        mh2.x = mhr[f]; mh2.y = mhr[f];
        #pragma unroll
        for (int k = 0; k < 6; ++k) {
            asm volatile("v_pk_fma_f32 %0, %1, %2, %0"
                         : "+v"(pz2[k]) : "v"(y2[k]), "v"(mz2));
            asm volatile("v_pk_fma_f32 %0, %1, %2, %0"
                         : "+v"(ph2[k]) : "v"(y2[k]), "v"(mh2));
        }
    }
    float acc = 0.f;
    #pragma unroll
    for (int k = 0; k < 6; ++k) {
        #pragma unroll
        for (int h = 0; h < 2; ++h) {
            float pzv = (h == 0) ? pz2[k].x : pz2[k].y;
            float phv = (h == 0) ? ph2[k].x : ph2[k].y;
            // weights pre-scaled by log2e (z) / 2*log2e (h):
            // (1-z) = 1/(1+2^pz); tanh = 1 - 2/(1+2^ph)
            float ez, eh;
            asm("v_exp_f32 %0, %1" : "=v"(ez) : "v"(pzv));
            asm("v_exp_f32 %0, %1" : "=v"(eh) : "v"(phv));
            float omz = __builtin_amdgcn_rcpf(1.f + ez);
            float th  = 1.f - 2.f * __builtin_amdgcn_rcpf(1.f + eh);
            acc += pt[2*k + h] * omz * th;
        }
    }
    hlds[gg*33 + c0] = fmaxf(acc, 0.f);
    __syncthreads();                 // single-wave: trivial

    // ---- head phase: 2 nodes x 12 outputs ----
    if (tid < 2*TD) {
        int n0 = tid / TD, tt = tid - n0*TD;
        float v = head_b[tt];
        const float* hn = hlds + n0*33;
        #pragma unroll
        for (int cc = 0; cc < CD; ++cc) v += hn[cc] * headW[cc*TD + tt];
        out[(size_t)(blockIdx.x*2 + n0)*TD + tt] = v;
    }
}

extern "C" void kernel_launch(void* const* d_in, const int* in_sizes, int n_in,
                              void* d_out, int out_size, void* d_ws, size_t ws_size,
                              hipStream_t stream)
{
    const float* x      = (const float*)d_in[0];
    const int*   ei     = (const int*)  d_in[1];
    const float* ef     = (const float*)d_in[2];
    const float* feat_W = (const float*)d_in[3];
    const float* feat_b = (const float*)d_in[4];
    const float* ef_W   = (const float*)d_in[5];
    const float* ef_b   = (const float*)d_in[6];
    const float* att    = (const float*)d_in[7];
    const float* czW    = (const float*)d_in[8];
    const float* czb    = (const float*)d_in[9];
    const float* chW    = (const float*)d_in[12];
    const float* chb    = (const float*)d_in[13];
    const float* lzW    = (const float*)d_in[14];
    const float* lzb    = (const float*)d_in[15];
    const float* lhW    = (const float*)d_in[18];
    const float* lhb    = (const float*)d_in[19];
    const float* hW     = (const float*)d_in[20];
    const float* hb     = (const float*)d_in[21];
    float* out = (float*)d_out;

    unsigned long long* dc  = (unsigned long long*)d_ws;   // NN u64 (zeroed)
    float*              cst = (float*)(dc + NN);           // 1024
    int2*               ep  = (int2*)(cst + 1024);         // NN*SLOTS pairs

    kInit<<<ZB + 1, 512, 0, stream>>>((float4*)dc, feat_W, feat_b, att,
                                      czW, czb, chW, chb, lzW, lzb, lhW, lhb, cst);
    kB1<<<(NE + 255)/256, 256, 0, stream>>>(ei, ef, ef_W, ef_b, dc, ep);
    kGE<<<NN/2, 64, 0, stream>>>(x, dc, ep, cst, hW, hb, out);
}